// Round 1
// baseline (599.255 us; speedup 1.0000x reference)
//
#include <hip/hip_runtime.h>

// Problem constants: b=16, c=128, groups=8, h=w=64 -> n=4096
#define NB   16
#define NC   128
#define NPOS 4096

typedef short bf16x8 __attribute__((ext_vector_type(8)));  // 8 bf16 in 4 VGPRs (guide-verified frag type)
typedef float f32x4  __attribute__((ext_vector_type(4)));

static __device__ __forceinline__ unsigned short f2bf(float f) {
    unsigned int u = __builtin_bit_cast(unsigned int, f);
    u += 0x7FFFu + ((u >> 16) & 1u);   // round-to-nearest-even
    return (unsigned short)(u >> 16);
}

// ---------------- K0: fp32 -> bf16 weight conversion (64 blocks x 256) ----------------
__global__ void wconv_kernel(const float* __restrict__ wq, const float* __restrict__ wk,
                             const float* __restrict__ wv, const float* __restrict__ wf,
                             unsigned short* __restrict__ oq, unsigned short* __restrict__ ok,
                             unsigned short* __restrict__ ov, unsigned short* __restrict__ of) {
    int i = blockIdx.x * 256 + threadIdx.x;   // 16384 elements each
    oq[i] = f2bf(wq[i]); ok[i] = f2bf(wk[i]); ov[i] = f2bf(wv[i]); of[i] = f2bf(wf[i]);
}

// ---------------- K1: GroupNorm stats, one block per (b,g), 128 blocks ----------------
__global__ void gnstat_kernel(const float* __restrict__ x, float* __restrict__ mean,
                              float* __restrict__ rstd) {
    int bg = blockIdx.x;                       // b*8+g ; group = 16 ch * 4096 = 65536 contiguous floats
    const float* p = x + (size_t)bg * 65536;
    int t = threadIdx.x;
    float s = 0.f, q = 0.f;
    for (int it = 0; it < 64; ++it) {
        f32x4 v = *(const f32x4*)(p + it * 1024 + t * 4);
        s += v[0] + v[1] + v[2] + v[3];
        q += v[0] * v[0] + v[1] * v[1] + v[2] * v[2] + v[3] * v[3];
    }
    for (int m = 1; m < 64; m <<= 1) { s += __shfl_xor(s, m); q += __shfl_xor(q, m); }
    __shared__ float ls[4], lq[4];
    int w = t >> 6;
    if ((t & 63) == 0) { ls[w] = s; lq[w] = q; }
    __syncthreads();
    if (t == 0) {
        s = ls[0] + ls[1] + ls[2] + ls[3];
        q = lq[0] + lq[1] + lq[2] + lq[3];
        float mu  = s * (1.0f / 65536.0f);
        float var = q * (1.0f / 65536.0f) - mu * mu;
        mean[bg] = mu;
        rstd[bg] = rsqrtf(var + 1e-5f);
    }
}

// ---------------- K2: GN-apply + QKV GEMMs (grid 64 x 16, 256 thr) ----------------
// Outputs: qT,kT as [b][n][c] bf16 (for contiguous-c frag loads), v as [b][c][n] bf16.
__global__ __launch_bounds__(256) void qkv_kernel(
    const float* __restrict__ x, const float* __restrict__ gnw, const float* __restrict__ gnb,
    const float* __restrict__ mean, const float* __restrict__ rstd,
    const unsigned short* __restrict__ wqb, const unsigned short* __restrict__ wkb,
    const unsigned short* __restrict__ wvb,
    const float* __restrict__ bq, const float* __restrict__ bk, const float* __restrict__ bv,
    unsigned short* __restrict__ qT, unsigned short* __restrict__ kT, unsigned short* __restrict__ vv) {
    __shared__ __attribute__((aligned(16))) unsigned short xn[64 * 136];  // [i][c], stride 136 (pad 8)
    const int b = blockIdx.y, i0 = blockIdx.x * 64;
    const int t = threadIdx.x;

    // Stage normalized x tile into LDS as [i][c] bf16 (pack c,c+1 per 32-bit write)
    {
        int iL = (t & 15) * 4;
        int cb = (t >> 4) * 2;
        for (int cg = 0; cg < 4; ++cg) {
            int c = cg * 32 + cb;
            int g = c >> 4;
            float mu = mean[b * 8 + g], rs = rstd[b * 8 + g];
            float ga0 = gnw[c] * rs,     be0 = gnb[c]     - mu * ga0;
            float ga1 = gnw[c + 1] * rs, be1 = gnb[c + 1] - mu * ga1;
            const float* p0 = x + ((size_t)(b * NC + c)) * NPOS + i0 + iL;
            f32x4 v0 = *(const f32x4*)p0;
            f32x4 v1 = *(const f32x4*)(p0 + NPOS);
            for (int e = 0; e < 4; ++e) {
                unsigned int u = (unsigned)f2bf(v0[e] * ga0 + be0) |
                                 ((unsigned)f2bf(v1[e] * ga1 + be1) << 16);
                *(unsigned int*)&xn[(iL + e) * 136 + c] = u;
            }
        }
    }
    __syncthreads();

    const int lane = t & 63, w = t >> 6, quad = lane >> 4, li = lane & 15;

    // ---- q^T, k^T: D[i][o] = sum_c xnT[i][c] * W[o][c]  (A = xnT from LDS, B = W rows)
    bf16x8 ax[4];
    for (int kc = 0; kc < 4; ++kc)
        ax[kc] = *(const bf16x8*)&xn[(w * 16 + li) * 136 + kc * 32 + quad * 8];
    for (int wt = 0; wt < 2; ++wt) {
        const unsigned short* W = wt ? wkb : wqb;
        const float* bias = wt ? bk : bq;
        unsigned short* dst = wt ? kT : qT;
        for (int nt = 0; nt < 8; ++nt) {
            f32x4 d = {0.f, 0.f, 0.f, 0.f};
            for (int kc = 0; kc < 4; ++kc) {
                bf16x8 bw = *(const bf16x8*)&W[(nt * 16 + li) * 128 + kc * 32 + quad * 8];
                d = __builtin_amdgcn_mfma_f32_16x16x32_bf16(ax[kc], bw, d, 0, 0, 0);
            }
            float bb = bias[nt * 16 + li];
            size_t base = ((size_t)b * NPOS + i0 + w * 16 + quad * 4) * NC + nt * 16 + li;
            for (int rr = 0; rr < 4; ++rr)
                dst[base + (size_t)rr * NC] = f2bf(d[rr] + bb);
        }
    }

    // ---- v: D[o][i] = sum_c wv[o][c] * xn[c][i]  (A = wv rows, B = xnT from LDS)
    bf16x8 av[2][4];
    for (int mt = 0; mt < 2; ++mt)
        for (int kc = 0; kc < 4; ++kc)
            av[mt][kc] = *(const bf16x8*)&wvb[((w * 2 + mt) * 16 + li) * 128 + kc * 32 + quad * 8];
    for (int nt = 0; nt < 4; ++nt) {
        bf16x8 bx[4];
        for (int kc = 0; kc < 4; ++kc)
            bx[kc] = *(const bf16x8*)&xn[(nt * 16 + li) * 136 + kc * 32 + quad * 8];
        for (int mt = 0; mt < 2; ++mt) {
            f32x4 d = {0.f, 0.f, 0.f, 0.f};
            for (int kc = 0; kc < 4; ++kc)
                d = __builtin_amdgcn_mfma_f32_16x16x32_bf16(av[mt][kc], bx[kc], d, 0, 0, 0);
            int o0 = (w * 2 + mt) * 16 + quad * 4;
            for (int rr = 0; rr < 4; ++rr) {
                float val = d[rr] + bv[o0 + rr];
                vv[((size_t)(b * NC + o0 + rr)) * NPOS + i0 + nt * 16 + li] = f2bf(val);
            }
        }
    }
}

// ---------------- K3: flash attention (grid 64 x 16, 256 thr = 4 waves x 16 q-rows) ----------------
__global__ __launch_bounds__(256) void flash_kernel(
    const unsigned short* __restrict__ qT, const unsigned short* __restrict__ kT,
    const unsigned short* __restrict__ vv, unsigned short* __restrict__ oT) {
    __shared__ __attribute__((aligned(16))) unsigned short kt[64 * 136];   // [j][c] stride 136
    __shared__ __attribute__((aligned(16))) unsigned short vt[128 * 72];   // [c][j] stride 72
    __shared__ __attribute__((aligned(16))) unsigned short pt[4][16 * 72]; // per-wave P [i][j] stride 72
    const int b = blockIdx.y, i0 = blockIdx.x * 64;
    const int t = threadIdx.x, lane = t & 63, w = t >> 6, quad = lane >> 4, li = lane & 15;
    const float SC = 0.12751743075095855f;  // log2(e)/sqrt(128)

    bf16x8 aq[4];
    for (int kc = 0; kc < 4; ++kc)
        aq[kc] = *(const bf16x8*)&qT[((size_t)b * NPOS + i0 + w * 16 + li) * NC + kc * 32 + quad * 8];

    float mrow[4] = {-1e30f, -1e30f, -1e30f, -1e30f};
    float lrow[4] = {0.f, 0.f, 0.f, 0.f};
    f32x4 acc[8];
    for (int ct = 0; ct < 8; ++ct) acc[ct] = (f32x4){0.f, 0.f, 0.f, 0.f};

    const int kjj = t >> 2, kcc = (t & 3) * 32;   // K stage mapping
    const int vc  = t >> 1, vjc = (t & 1) * 32;   // V stage mapping

    for (int jt = 0; jt < 64; ++jt) {
        const int j0 = jt * 64;
        __syncthreads();   // previous iter's LDS reads done
        {
            const unsigned short* sk = &kT[((size_t)b * NPOS + j0 + kjj) * NC + kcc];
            unsigned short* dk = &kt[kjj * 136 + kcc];
            for (int m = 0; m < 4; ++m) *(bf16x8*)(dk + m * 8) = *(const bf16x8*)(sk + m * 8);
            const unsigned short* sv = &vv[((size_t)(b * NC + vc)) * NPOS + j0 + vjc];
            unsigned short* dv = &vt[vc * 72 + vjc];
            for (int m = 0; m < 4; ++m) *(bf16x8*)(dv + m * 8) = *(const bf16x8*)(sv + m * 8);
        }
        __syncthreads();

        // S = Q^T K  (16 i x 64 j per wave)
        f32x4 s[4];
        for (int nt = 0; nt < 4; ++nt) {
            f32x4 z = {0.f, 0.f, 0.f, 0.f};
            for (int kc = 0; kc < 4; ++kc) {
                bf16x8 bk = *(const bf16x8*)&kt[(nt * 16 + li) * 136 + kc * 32 + quad * 8];
                z = __builtin_amdgcn_mfma_f32_16x16x32_bf16(aq[kc], bk, z, 0, 0, 0);
            }
            s[nt] = z;
        }

        // online softmax (rows quad*4+rr; values spread over 16 lanes of the quad)
        float al[4];
        for (int rr = 0; rr < 4; ++rr) {
            float tm = fmaxf(fmaxf(s[0][rr], s[1][rr]), fmaxf(s[2][rr], s[3][rr])) * SC;
            tm = fmaxf(tm, __shfl_xor(tm, 1));
            tm = fmaxf(tm, __shfl_xor(tm, 2));
            tm = fmaxf(tm, __shfl_xor(tm, 4));
            tm = fmaxf(tm, __shfl_xor(tm, 8));
            float mn = fmaxf(mrow[rr], tm);
            al[rr] = __builtin_amdgcn_exp2f(mrow[rr] - mn);
            mrow[rr] = mn;
        }
        float rs[4] = {0.f, 0.f, 0.f, 0.f};
        for (int nt = 0; nt < 4; ++nt)
            for (int rr = 0; rr < 4; ++rr) {
                float p = __builtin_amdgcn_exp2f(s[nt][rr] * SC - mrow[rr]);
                rs[rr] += p;
                pt[w][(quad * 4 + rr) * 72 + nt * 16 + li] = f2bf(p);
            }
        for (int rr = 0; rr < 4; ++rr) {
            float v2 = rs[rr];
            v2 += __shfl_xor(v2, 1); v2 += __shfl_xor(v2, 2);
            v2 += __shfl_xor(v2, 4); v2 += __shfl_xor(v2, 8);
            lrow[rr] = lrow[rr] * al[rr] + v2;
        }
        for (int ct = 0; ct < 8; ++ct) {
            f32x4 a = acc[ct];
            a[0] *= al[0]; a[1] *= al[1]; a[2] *= al[2]; a[3] *= al[3];
            acc[ct] = a;
        }

        // O += P V  (P via LDS round-trip to A-layout)
        bf16x8 ap[2];
        for (int k2 = 0; k2 < 2; ++k2)
            ap[k2] = *(const bf16x8*)&pt[w][li * 72 + k2 * 32 + quad * 8];
        for (int ct = 0; ct < 8; ++ct)
            for (int k2 = 0; k2 < 2; ++k2) {
                bf16x8 bv = *(const bf16x8*)&vt[(ct * 16 + li) * 72 + k2 * 32 + quad * 8];
                acc[ct] = __builtin_amdgcn_mfma_f32_16x16x32_bf16(ap[k2], bv, acc[ct], 0, 0, 0);
            }
    }

    float inv[4];
    for (int rr = 0; rr < 4; ++rr) inv[rr] = __builtin_amdgcn_rcpf(lrow[rr]);
    for (int ct = 0; ct < 8; ++ct)
        for (int rr = 0; rr < 4; ++rr)
            oT[((size_t)b * NPOS + i0 + w * 16 + quad * 4 + rr) * NC + ct * 16 + li] =
                f2bf(acc[ct][rr] * inv[rr]);
}

// ---------------- K4: out = wf @ o + bf + x  (grid 64 x 16, 256 thr) ----------------
__global__ __launch_bounds__(256) void proj_kernel(
    const unsigned short* __restrict__ oT, const unsigned short* __restrict__ wfb,
    const float* __restrict__ bf_, const float* __restrict__ x, float* __restrict__ out) {
    const int b = blockIdx.y, i0 = blockIdx.x * 64;
    const int t = threadIdx.x, lane = t & 63, w = t >> 6, quad = lane >> 4, li = lane & 15;
    bf16x8 aw[2][4];
    for (int mt = 0; mt < 2; ++mt)
        for (int kc = 0; kc < 4; ++kc)
            aw[mt][kc] = *(const bf16x8*)&wfb[((w * 2 + mt) * 16 + li) * 128 + kc * 32 + quad * 8];
    for (int nt = 0; nt < 4; ++nt) {
        bf16x8 bo[4];
        for (int kc = 0; kc < 4; ++kc)
            bo[kc] = *(const bf16x8*)&oT[((size_t)b * NPOS + i0 + nt * 16 + li) * NC + kc * 32 + quad * 8];
        for (int mt = 0; mt < 2; ++mt) {
            f32x4 d = {0.f, 0.f, 0.f, 0.f};
            for (int kc = 0; kc < 4; ++kc)
                d = __builtin_amdgcn_mfma_f32_16x16x32_bf16(aw[mt][kc], bo[kc], d, 0, 0, 0);
            int o0 = (w * 2 + mt) * 16 + quad * 4;
            for (int rr = 0; rr < 4; ++rr) {
                size_t idx = ((size_t)(b * NC + o0 + rr)) * NPOS + i0 + nt * 16 + li;
                out[idx] = d[rr] + bf_[o0 + rr] + x[idx];
            }
        }
    }
}

extern "C" void kernel_launch(void* const* d_in, const int* in_sizes, int n_in,
                              void* d_out, int out_size, void* d_ws, size_t ws_size,
                              hipStream_t stream) {
    const float* x   = (const float*)d_in[0];
    const float* gnw = (const float*)d_in[1];
    const float* gnb = (const float*)d_in[2];
    const float* wq  = (const float*)d_in[3];
    const float* bq  = (const float*)d_in[4];
    const float* wk  = (const float*)d_in[5];
    const float* bk  = (const float*)d_in[6];
    const float* wv  = (const float*)d_in[7];
    const float* bv  = (const float*)d_in[8];
    const float* wf  = (const float*)d_in[9];
    const float* bf_ = (const float*)d_in[10];
    float* out = (float*)d_out;

    char* ws = (char*)d_ws;
    float* mean = (float*)(ws + 0);            // 128 f
    float* rstd = (float*)(ws + 512);          // 128 f
    unsigned short* wqb = (unsigned short*)(ws + 1024);
    unsigned short* wkb = wqb + 16384;
    unsigned short* wvb = wkb + 16384;
    unsigned short* wfb = wvb + 16384;
    unsigned short* qT  = (unsigned short*)(ws + 132096);          // [b][n][c] bf16
    unsigned short* kT  = qT + (size_t)NB * NPOS * NC;             // [b][n][c]
    unsigned short* vv  = kT + (size_t)NB * NPOS * NC;             // [b][c][n]
    unsigned short* oT  = vv + (size_t)NB * NPOS * NC;             // [b][n][c]

    wconv_kernel<<<64, 256, 0, stream>>>(wq, wk, wv, wf, wqb, wkb, wvb, wfb);
    gnstat_kernel<<<128, 256, 0, stream>>>(x, mean, rstd);
    dim3 g(64, 16);
    qkv_kernel<<<g, 256, 0, stream>>>(x, gnw, gnb, mean, rstd, wqb, wkb, wvb, bq, bk, bv, qT, kT, vv);
    flash_kernel<<<g, 256, 0, stream>>>(qT, kT, vv, oT);
    proj_kernel<<<g, 256, 0, stream>>>(oT, wfb, bf_, x, out);
}

// Round 2
// 352.308 us; speedup vs baseline: 1.7009x; 1.7009x over previous
//
#include <hip/hip_runtime.h>

// Problem constants: b=16, c=128, groups=8, h=w=64 -> n=4096
#define NB   16
#define NC   128
#define NPOS 4096

typedef short bf16x8 __attribute__((ext_vector_type(8)));   // 8 bf16 (4 VGPRs)
typedef float f32x4  __attribute__((ext_vector_type(4)));
typedef float f32x16 __attribute__((ext_vector_type(16)));

static __device__ __forceinline__ unsigned short f2bf(float f) {
    unsigned int u = __builtin_bit_cast(unsigned int, f);
    u += 0x7FFFu + ((u >> 16) & 1u);   // round-to-nearest-even
    return (unsigned short)(u >> 16);
}

// pack two floats -> bf16x2 dword (truncating; callers pre-scale by 1+2^-9 to center)
static __device__ __forceinline__ unsigned int pkbf(float hi, float lo) {
    return __builtin_amdgcn_perm(__builtin_bit_cast(unsigned int, hi),
                                 __builtin_bit_cast(unsigned int, lo), 0x07060302u);
}

// ---------------- K0: fp32 -> bf16 weight conversion (64 blocks x 256) ----------------
__global__ void wconv_kernel(const float* __restrict__ wq, const float* __restrict__ wk,
                             const float* __restrict__ wv, const float* __restrict__ wf,
                             unsigned short* __restrict__ oq, unsigned short* __restrict__ ok,
                             unsigned short* __restrict__ ov, unsigned short* __restrict__ of) {
    int i = blockIdx.x * 256 + threadIdx.x;
    oq[i] = f2bf(wq[i]); ok[i] = f2bf(wk[i]); ov[i] = f2bf(wv[i]); of[i] = f2bf(wf[i]);
}

// ---------------- K1: GroupNorm stats, one block per (b,g), 128 blocks ----------------
__global__ void gnstat_kernel(const float* __restrict__ x, float* __restrict__ mean,
                              float* __restrict__ rstd) {
    int bg = blockIdx.x;
    const float* p = x + (size_t)bg * 65536;
    int t = threadIdx.x;
    float s = 0.f, q = 0.f;
    for (int it = 0; it < 64; ++it) {
        f32x4 v = *(const f32x4*)(p + it * 1024 + t * 4);
        s += v[0] + v[1] + v[2] + v[3];
        q += v[0] * v[0] + v[1] * v[1] + v[2] * v[2] + v[3] * v[3];
    }
    for (int m = 1; m < 64; m <<= 1) { s += __shfl_xor(s, m); q += __shfl_xor(q, m); }
    __shared__ float ls[4], lq[4];
    int w = t >> 6;
    if ((t & 63) == 0) { ls[w] = s; lq[w] = q; }
    __syncthreads();
    if (t == 0) {
        s = ls[0] + ls[1] + ls[2] + ls[3];
        q = lq[0] + lq[1] + lq[2] + lq[3];
        float mu  = s * (1.0f / 65536.0f);
        float var = q * (1.0f / 65536.0f) - mu * mu;
        mean[bg] = mu;
        rstd[bg] = rsqrtf(var + 1e-5f);
    }
}

// ---------------- K2: GN-apply + QKV GEMMs (grid 64 x 16, 256 thr) ----------------
__global__ __launch_bounds__(256) void qkv_kernel(
    const float* __restrict__ x, const float* __restrict__ gnw, const float* __restrict__ gnb,
    const float* __restrict__ mean, const float* __restrict__ rstd,
    const unsigned short* __restrict__ wqb, const unsigned short* __restrict__ wkb,
    const unsigned short* __restrict__ wvb,
    const float* __restrict__ bq, const float* __restrict__ bk, const float* __restrict__ bv,
    unsigned short* __restrict__ qT, unsigned short* __restrict__ kT, unsigned short* __restrict__ vv) {
    __shared__ __attribute__((aligned(16))) unsigned short xn[64 * 136];  // [i][c], stride 136
    const int b = blockIdx.y, i0 = blockIdx.x * 64;
    const int t = threadIdx.x;
    {
        int iL = (t & 15) * 4;
        int cb = (t >> 4) * 2;
        for (int cg = 0; cg < 4; ++cg) {
            int c = cg * 32 + cb;
            int g = c >> 4;
            float mu = mean[b * 8 + g], rs = rstd[b * 8 + g];
            float ga0 = gnw[c] * rs,     be0 = gnb[c]     - mu * ga0;
            float ga1 = gnw[c + 1] * rs, be1 = gnb[c + 1] - mu * ga1;
            const float* p0 = x + ((size_t)(b * NC + c)) * NPOS + i0 + iL;
            f32x4 v0 = *(const f32x4*)p0;
            f32x4 v1 = *(const f32x4*)(p0 + NPOS);
            for (int e = 0; e < 4; ++e) {
                unsigned int u = (unsigned)f2bf(v0[e] * ga0 + be0) |
                                 ((unsigned)f2bf(v1[e] * ga1 + be1) << 16);
                *(unsigned int*)&xn[(iL + e) * 136 + c] = u;
            }
        }
    }
    __syncthreads();

    const int lane = t & 63, w = t >> 6, quad = lane >> 4, li = lane & 15;

    bf16x8 ax[4];
    for (int kc = 0; kc < 4; ++kc)
        ax[kc] = *(const bf16x8*)&xn[(w * 16 + li) * 136 + kc * 32 + quad * 8];
    for (int wt = 0; wt < 2; ++wt) {
        const unsigned short* W = wt ? wkb : wqb;
        const float* bias = wt ? bk : bq;
        unsigned short* dst = wt ? kT : qT;
        for (int nt = 0; nt < 8; ++nt) {
            f32x4 d = {0.f, 0.f, 0.f, 0.f};
            for (int kc = 0; kc < 4; ++kc) {
                bf16x8 bw = *(const bf16x8*)&W[(nt * 16 + li) * 128 + kc * 32 + quad * 8];
                d = __builtin_amdgcn_mfma_f32_16x16x32_bf16(ax[kc], bw, d, 0, 0, 0);
            }
            float bb = bias[nt * 16 + li];
            size_t base = ((size_t)b * NPOS + i0 + w * 16 + quad * 4) * NC + nt * 16 + li;
            for (int rr = 0; rr < 4; ++rr)
                dst[base + (size_t)rr * NC] = f2bf(d[rr] + bb);
        }
    }

    bf16x8 av[2][4];
    for (int mt = 0; mt < 2; ++mt)
        for (int kc = 0; kc < 4; ++kc)
            av[mt][kc] = *(const bf16x8*)&wvb[((w * 2 + mt) * 16 + li) * 128 + kc * 32 + quad * 8];
    for (int nt = 0; nt < 4; ++nt) {
        bf16x8 bx[4];
        for (int kc = 0; kc < 4; ++kc)
            bx[kc] = *(const bf16x8*)&xn[(nt * 16 + li) * 136 + kc * 32 + quad * 8];
        for (int mt = 0; mt < 2; ++mt) {
            f32x4 d = {0.f, 0.f, 0.f, 0.f};
            for (int kc = 0; kc < 4; ++kc)
                d = __builtin_amdgcn_mfma_f32_16x16x32_bf16(av[mt][kc], bx[kc], d, 0, 0, 0);
            int o0 = (w * 2 + mt) * 16 + quad * 4;
            for (int rr = 0; rr < 4; ++rr) {
                float val = d[rr] + bv[o0 + rr];
                vv[((size_t)(b * NC + o0 + rr)) * NPOS + i0 + nt * 16 + li] = f2bf(val);
            }
        }
    }
}

// ---------------- K3: flash attention, 32x32x16 MFMA ----------------
// grid (16 b, 32 i-tiles), 256 thr = 4 waves x 32 q-rows. j-tile = 64.
// S^T = K Q^T  (A = K rows from LDS, B = Q cols in regs) -> softmax state scalar per lane.
// All LDS XOR-swizzled: <=2-way bank aliasing everywhere (free per m136).
__global__ __launch_bounds__(256, 2) void flash_kernel(
    const unsigned short* __restrict__ qT, const unsigned short* __restrict__ kT,
    const unsigned short* __restrict__ vv, unsigned short* __restrict__ oT) {
    __shared__ __attribute__((aligned(16))) unsigned short kt[64 * 128];   // [j][c] swizzled
    __shared__ __attribute__((aligned(16))) unsigned short vt[128 * 64];   // [c][j] swizzled
    __shared__ __attribute__((aligned(16))) unsigned short pt[4 * 2048];   // per-wave P [i][j] swizzled
    const int b = blockIdx.x, i0 = blockIdx.y * 128;
    const int t = threadIdx.x, lane = t & 63, w = t >> 6;
    const int il = lane & 31, h = lane >> 5;
    const float SC = 0.12751743075095855f;  // log2(e)/sqrt(128)
    const float CP = 1.001953125f;          // 1+2^-9: centers v_perm truncation

    // Q B-fragments, held in registers for the whole kernel (8 frags = 32 VGPRs)
    bf16x8 qb[8];
    for (int kc = 0; kc < 8; ++kc)
        qb[kc] = *(const bf16x8*)&qT[((size_t)b * NPOS + i0 + w * 32 + il) * NC + kc * 16 + h * 8];

    float mrow = -1e30f, lrow = 0.f;
    f32x16 acc[4];
    for (int ct = 0; ct < 4; ++ct)
        for (int r = 0; r < 16; ++r) acc[ct][r] = 0.f;

    const int kjj = t >> 2, kq = t & 3;     // K stage: row j, c-chunk
    const int vc  = t >> 1, vq = t & 1;     // V stage: row c, j-chunk
    const unsigned short* pw = &pt[w * 2048];

    for (int jt = 0; jt < 64; ++jt) {
        const int j0 = jt * 64;
        __syncthreads();
        {
            const unsigned short* sk = &kT[((size_t)b * NPOS + j0 + kjj) * NC + kq * 32];
            unsigned short* dkb = &kt[kjj * 128];
            const unsigned short* sv = &vv[((size_t)(b * NC + vc)) * NPOS + j0 + vq * 32];
            unsigned short* dvb = &vt[vc * 64];
            for (int m = 0; m < 4; ++m) {
                *(bf16x8*)(dkb + (((kq * 4 + m) ^ (kjj & 7)) << 3)) = *(const bf16x8*)(sk + m * 8);
                *(bf16x8*)(dvb + (((vq * 4 + m) ^ (vc  & 7)) << 3)) = *(const bf16x8*)(sv + m * 8);
            }
        }
        __syncthreads();

        // S^T tiles: st0 = j 0..31, st1 = j 32..63 ; col = i = il
        f32x16 st0, st1;
        for (int r = 0; r < 16; ++r) { st0[r] = 0.f; st1[r] = 0.f; }
        for (int kc = 0; kc < 8; ++kc) {
            bf16x8 a0 = *(const bf16x8*)&kt[il * 128 + (((kc * 2 + h) ^ (il & 7)) << 3)];
            bf16x8 a1 = *(const bf16x8*)&kt[(32 + il) * 128 + (((kc * 2 + h) ^ (il & 7)) << 3)];
            st0 = __builtin_amdgcn_mfma_f32_32x32x16_bf16(a0, qb[kc], st0, 0, 0, 0);
            st1 = __builtin_amdgcn_mfma_f32_32x32x16_bf16(a1, qb[kc], st1, 0, 0, 0);
        }

        // online softmax: column i = il; state scalar per lane
        float mx = st0[0];
        for (int r = 1; r < 16; ++r) mx = fmaxf(mx, st0[r]);
        for (int r = 0; r < 16; ++r) mx = fmaxf(mx, st1[r]);
        mx *= SC;
        mx = fmaxf(mx, __shfl_xor(mx, 32));
        float mn = fmaxf(mrow, mx);
        float alpha = __builtin_amdgcn_exp2f(mrow - mn);
        mrow = mn;

        float p0[16], p1[16], rs = 0.f;
        for (int r = 0; r < 16; ++r) {
            p0[r] = __builtin_amdgcn_exp2f(st0[r] * SC - mn);
            p1[r] = __builtin_amdgcn_exp2f(st1[r] * SC - mn);
            rs += p0[r] + p1[r];
        }
        rs += __shfl_xor(rs, 32);
        lrow = lrow * alpha + rs;

        // P -> LDS [i][j] swizzled: per (tile,r2) one b64 write of 4 consecutive j
        for (int r2 = 0; r2 < 4; ++r2) {
            unsigned short* dp = (unsigned short*)&pw[il * 64 + 4 * h];
            unsigned int a0 = pkbf(p0[r2 * 4 + 1] * CP, p0[r2 * 4 + 0] * CP);
            unsigned int a1 = pkbf(p0[r2 * 4 + 3] * CP, p0[r2 * 4 + 2] * CP);
            unsigned int b0 = pkbf(p1[r2 * 4 + 1] * CP, p1[r2 * 4 + 0] * CP);
            unsigned int b1 = pkbf(p1[r2 * 4 + 3] * CP, p1[r2 * 4 + 2] * CP);
            *(unsigned int*)(dp + (((0 * 4 + r2) ^ (il & 7)) << 3))     = a0;
            *(unsigned int*)(dp + (((0 * 4 + r2) ^ (il & 7)) << 3) + 2) = a1;
            *(unsigned int*)(dp + (((1 * 4 + r2) ^ (il & 7)) << 3))     = b0;
            *(unsigned int*)(dp + (((1 * 4 + r2) ^ (il & 7)) << 3) + 2) = b1;
        }

        // rescale accumulator: alpha lives at lane i; acc row i = (r&3)+8*(r>>2)+4*h
        float alb[16];
        for (int r = 0; r < 16; ++r)
            alb[r] = __shfl(alpha, (r & 3) + 8 * (r >> 2) + 4 * h);
        for (int ct = 0; ct < 4; ++ct)
            for (int r = 0; r < 16; ++r) acc[ct][r] *= alb[r];

        // O += P V : A = P frags from LDS, B = V frags from LDS
        bf16x8 ap[4];
        for (int kc2 = 0; kc2 < 4; ++kc2)
            ap[kc2] = *(const bf16x8*)&pw[il * 64 + (((kc2 * 2 + h) ^ (il & 7)) << 3)];
        for (int ct = 0; ct < 4; ++ct) {
            int cr = ct * 32 + il;
            for (int kc2 = 0; kc2 < 4; ++kc2) {
                bf16x8 bv = *(const bf16x8*)&vt[cr * 64 + (((kc2 * 2 + h) ^ (cr & 7)) << 3)];
                acc[ct] = __builtin_amdgcn_mfma_f32_32x32x16_bf16(ap[kc2], bv, acc[ct], 0, 0, 0);
            }
        }
    }

    float inv = __builtin_amdgcn_rcpf(lrow);
    float invb[16];
    for (int r = 0; r < 16; ++r)
        invb[r] = __shfl(inv, (r & 3) + 8 * (r >> 2) + 4 * h);
    for (int ct = 0; ct < 4; ++ct)
        for (int r = 0; r < 16; ++r) {
            int ir = (r & 3) + 8 * (r >> 2) + 4 * h;
            oT[((size_t)b * NPOS + i0 + w * 32 + ir) * NC + ct * 32 + il] =
                f2bf(acc[ct][r] * invb[r]);
        }
}

// ---------------- K4: out = wf @ o + bf + x  (grid 64 x 16, 256 thr) ----------------
__global__ __launch_bounds__(256) void proj_kernel(
    const unsigned short* __restrict__ oT, const unsigned short* __restrict__ wfb,
    const float* __restrict__ bf_, const float* __restrict__ x, float* __restrict__ out) {
    const int b = blockIdx.y, i0 = blockIdx.x * 64;
    const int t = threadIdx.x, lane = t & 63, w = t >> 6, quad = lane >> 4, li = lane & 15;
    bf16x8 aw[2][4];
    for (int mt = 0; mt < 2; ++mt)
        for (int kc = 0; kc < 4; ++kc)
            aw[mt][kc] = *(const bf16x8*)&wfb[((w * 2 + mt) * 16 + li) * 128 + kc * 32 + quad * 8];
    for (int nt = 0; nt < 4; ++nt) {
        bf16x8 bo[4];
        for (int kc = 0; kc < 4; ++kc)
            bo[kc] = *(const bf16x8*)&oT[((size_t)b * NPOS + i0 + nt * 16 + li) * NC + kc * 32 + quad * 8];
        for (int mt = 0; mt < 2; ++mt) {
            f32x4 d = {0.f, 0.f, 0.f, 0.f};
            for (int kc = 0; kc < 4; ++kc)
                d = __builtin_amdgcn_mfma_f32_16x16x32_bf16(aw[mt][kc], bo[kc], d, 0, 0, 0);
            int o0 = (w * 2 + mt) * 16 + quad * 4;
            for (int rr = 0; rr < 4; ++rr) {
                size_t idx = ((size_t)(b * NC + o0 + rr)) * NPOS + i0 + nt * 16 + li;
                out[idx] = d[rr] + bf_[o0 + rr] + x[idx];
            }
        }
    }
}

extern "C" void kernel_launch(void* const* d_in, const int* in_sizes, int n_in,
                              void* d_out, int out_size, void* d_ws, size_t ws_size,
                              hipStream_t stream) {
    const float* x   = (const float*)d_in[0];
    const float* gnw = (const float*)d_in[1];
    const float* gnb = (const float*)d_in[2];
    const float* wq  = (const float*)d_in[3];
    const float* bq  = (const float*)d_in[4];
    const float* wk  = (const float*)d_in[5];
    const float* bk  = (const float*)d_in[6];
    const float* wv  = (const float*)d_in[7];
    const float* bv  = (const float*)d_in[8];
    const float* wf  = (const float*)d_in[9];
    const float* bf_ = (const float*)d_in[10];
    float* out = (float*)d_out;

    char* ws = (char*)d_ws;
    float* mean = (float*)(ws + 0);
    float* rstd = (float*)(ws + 512);
    unsigned short* wqb = (unsigned short*)(ws + 1024);
    unsigned short* wkb = wqb + 16384;
    unsigned short* wvb = wkb + 16384;
    unsigned short* wfb = wvb + 16384;
    unsigned short* qT  = (unsigned short*)(ws + 132096);          // [b][n][c] bf16
    unsigned short* kT  = qT + (size_t)NB * NPOS * NC;             // [b][n][c]
    unsigned short* vv  = kT + (size_t)NB * NPOS * NC;             // [b][c][n]
    unsigned short* oT  = vv + (size_t)NB * NPOS * NC;             // [b][n][c]

    wconv_kernel<<<64, 256, 0, stream>>>(wq, wk, wv, wf, wqb, wkb, wvb, wfb);
    gnstat_kernel<<<128, 256, 0, stream>>>(x, mean, rstd);
    dim3 g(64, 16);
    qkv_kernel<<<g, 256, 0, stream>>>(x, gnw, gnb, mean, rstd, wqb, wkb, wvb, bq, bk, bv, qT, kT, vv);
    dim3 gf(16, 32);
    flash_kernel<<<gf, 256, 0, stream>>>(qT, kT, vv, oT);
    proj_kernel<<<g, 256, 0, stream>>>(oT, wfb, bf_, x, out);
}